// Round 2
// baseline (949.600 us; speedup 1.0000x reference)
//
#include <hip/hip_runtime.h>
#include <hip/hip_bf16.h>
#include <cstddef>

// z_e_x: [8,4096,512] fp32 -> BN=32768 rows; codebook: [8192,512] fp32.
// Outputs: codes [BN,512] fp32, zqx_tilde [BN,512] fp32, idx [BN] as fp32.
//
// Numerics (bit-exact-verified rounds 2-3): ref dist = fl(x_sq + 2*fl(dot)),
// cb_sq vanishes under fp32 rounding; fl(dot) = sequential fp32 fma chain
// k=0..511 ascending; argmin = first index.
//
// Strategy: bf16 MFMA computes approx dots (identical ascending-k 16x16x32
// chain as previous rounds -> bit-identical approx values). GEMM epilogue
// stores per-(row, 128-code block) min + 64-bit pair-mask of codes within
// blockmin + MARGIN. Select kernel expands candidates and rechecks each with
// the EXACT fp32 chain -> bit-exact argmin.
//
// GEMM: 256^2 8-phase schedule (learn_hip m201 template): BK=64, 8 waves
// (2Mx4N), 128 KiB dbuf LDS, 1 half-tile staged per phase, counted vmcnt(4)
// at phases 4/8 (never 0 in steady state), 2 raw barriers/phase, setprio
// around MFMA clusters, XOR-swizzled LDS reads with inverse-swizzled
// global_load_lds sources. (Round-1 bench was an infra failure; resubmit.)
constexpr int BN   = 32768;
constexpr int DDIM = 512;
constexpr int KC   = 8192;
#define MARGIN 3.0e-4f

typedef __attribute__((ext_vector_type(8))) short short8;    // 8 bf16
typedef __attribute__((ext_vector_type(4))) float f32x4;

__device__ inline unsigned short bf16_rne(float f) {
  unsigned u = __builtin_bit_cast(unsigned, f);
  unsigned r = u + 0x7FFFu + ((u >> 16) & 1u);
  return (unsigned short)(r >> 16);
}

#define GLL16(gp, lp)                                                         \
  __builtin_amdgcn_global_load_lds(                                           \
      (const __attribute__((address_space(1))) unsigned int*)(gp),            \
      (__attribute__((address_space(3))) unsigned int*)(lp), 16, 0, 0)

// ---------------- per-row squared norms (fp32 path, also used by recheck) ---
// DO NOT change summation order: tie behavior in vq_select depends on xsq
// bit pattern (verified absmax=0 with this exact order).
__global__ __launch_bounds__(256) void vq_xsq(const float* __restrict__ X,
                                              float* __restrict__ xsq) {
  const int wave = threadIdx.x >> 6;
  const int lane = threadIdx.x & 63;
  const int row = blockIdx.x * 4 + wave;
  const float4* r = (const float4*)(X + (size_t)row * DDIM);
  float s = 0.f;
#pragma unroll
  for (int t = 0; t < 2; ++t) {
    float4 v = r[lane + 64 * t];
    s += v.x * v.x + v.y * v.y + v.z * v.z + v.w * v.w;
  }
#pragma unroll
  for (int m = 32; m > 0; m >>= 1) s += __shfl_xor(s, m, 64);
  if (lane == 0) xsq[row] = s;
}

// ---------------- fp32 -> bf16 convert (RNE) ----------------
__global__ __launch_bounds__(256) void vq_cvt(const float* __restrict__ src,
                                              unsigned short* __restrict__ dst,
                                              int n4) {
  int i = blockIdx.x * 256 + threadIdx.x;
  const int stride = gridDim.x * 256;
  for (; i < n4; i += stride) {
    float4 v = ((const float4*)src)[i];
    ushort4 o;
    o.x = bf16_rne(v.x); o.y = bf16_rne(v.y);
    o.z = bf16_rne(v.z); o.w = bf16_rne(v.w);
    ((ushort4*)dst)[i] = o;
  }
}

// ---------------- bf16 MFMA GEMM, 256^2 tile, 8-phase schedule -------------
// 512 thr = 8 waves: wm = w>>2 (2 M-groups), wn = w&3 (4 N-groups).
// Wave output rows: {hA*128 + wm*64 + m4*16 + quad*4 + reg}, hA,m4 in frag.
// Wave output cols: {hB*128 + wn*32 + n1*16 + c16}.
// LDS (128 KiB): A[buf][half][128 rows][8 slots*16B] at 0,   buf str 32768
//                B[buf][half][...]                   at 65536
// Swizzle: row r, chunk c (16B along K) stored at slot f = c ^ (r&7).
// global_load_lds writes linearly -> per-lane SOURCE is inverse-swizzled:
// lane l stages chunk q = (l&7)^((l>>3)&7) of row (site*64 + w*8 + (l>>3)).
// ds_read_b128 per frag: byte = r*128 + ((kk*4+quad)^(r&7))*16 -> 2-way
// bank aliasing only (free).
//
// Per iteration (tiles tE=2i -> buf0, tO=2i+1 -> buf1), phases P1..P8:
//  reads:  P1 buf0(A0,B0) P2 buf0(A0,B1) P3 buf0(A1,B1) P4 buf0(A1,B0)
//          P5..P8 same on buf1
//  stage:  P1 buf1.Ah1(tO)  P2 buf1.Bh0(tO)  P3 buf0.Ah0(tE+2)
//          P4 buf0.Bh1(tE+2) P5 buf0.Ah1(tE+2) P6 buf0.Bh0(tE+2)
//          P7 buf1.Ah0(tO+2) P8 buf1.Bh1(tO+2)
//  waits:  vmcnt(4) before barrier at P4 and P8 (2 half-tiles in flight);
//          last iteration: P4 -> vmcnt(0), P5..P8 no stage.
// Every stage target's last read is exactly one phase earlier (double
// barrier separates); every read is covered by the preceding vmcnt+barrier.
__global__ __launch_bounds__(512, 2) void vq_gemm8(const unsigned short* __restrict__ Xb,
                                                   const unsigned short* __restrict__ CBb,
                                                   float* __restrict__ BM,
                                                   unsigned int* __restrict__ Msk) {
  __shared__ __align__(16) unsigned char smem[131072];

  const int tid  = threadIdx.x;
  const int lane = tid & 63;
  const int w    = tid >> 6;
  const int wm   = w >> 2, wn = w & 3;
  const int quad = lane >> 4, c16 = lane & 15;
  const int row0 = blockIdx.x * 256;
  const int col0 = blockIdx.y * 256;

  // staging source bases (site0 rows w*8+(l>>3); site1 = +64 rows = +65536B)
  const int srow = w * 8 + (lane >> 3);
  const int qch  = (lane & 7) ^ ((lane >> 3) & 7);
  const unsigned char* pA = (const unsigned char*)Xb  + (size_t)(row0 + srow) * 1024 + qch * 16;
  const unsigned char* pB = (const unsigned char*)CBb + (size_t)(col0 + srow) * 1024 + qch * 16;

  // ds_read per-lane constants
  const int arow = wm * 64 + c16;
  const int brow = wn * 32 + c16;
  const int sx0  = ((0 + quad) ^ (c16 & 7)) * 16;   // kk=0 chunk slot
  const int sx1  = ((4 + quad) ^ (c16 & 7)) * 16;   // kk=1 chunk slot

  f32x4 acc[8][4];
#pragma unroll
  for (int i = 0; i < 8; ++i)
#pragma unroll
    for (int j = 0; j < 4; ++j) acc[i][j] = (f32x4)0.f;

  short8 a[4][2], b[2][2];

#define STG_A(BUF, H, KT)                                                              \
  do {                                                                                 \
    GLL16(pA + (size_t)(H) * 131072 + (KT) * 128,                                      \
          smem + (BUF) * 32768 + (H) * 16384 + w * 1024);                              \
    GLL16(pA + (size_t)(H) * 131072 + 65536 + (KT) * 128,                              \
          smem + (BUF) * 32768 + (H) * 16384 + 8192 + w * 1024);                       \
  } while (0)
#define STG_B(BUF, H, KT)                                                              \
  do {                                                                                 \
    GLL16(pB + (size_t)(H) * 131072 + (KT) * 128,                                      \
          smem + 65536 + (BUF) * 32768 + (H) * 16384 + w * 1024);                      \
    GLL16(pB + (size_t)(H) * 131072 + 65536 + (KT) * 128,                              \
          smem + 65536 + (BUF) * 32768 + (H) * 16384 + 8192 + w * 1024);               \
  } while (0)

#define LDA(BUF, H)                                                                    \
  do {                                                                                 \
    _Pragma("unroll") for (int m4_ = 0; m4_ < 4; ++m4_) {                              \
      a[m4_][0] = *(const short8*)(smem + (BUF) * 32768 + (H) * 16384 +                \
                                   (arow + m4_ * 16) * 128 + sx0);                     \
      a[m4_][1] = *(const short8*)(smem + (BUF) * 32768 + (H) * 16384 +                \
                                   (arow + m4_ * 16) * 128 + sx1);                     \
    }                                                                                  \
  } while (0)
#define LDB(BUF, H)                                                                    \
  do {                                                                                 \
    _Pragma("unroll") for (int n1_ = 0; n1_ < 2; ++n1_) {                              \
      b[n1_][0] = *(const short8*)(smem + 65536 + (BUF) * 32768 + (H) * 16384 +        \
                                   (brow + n1_ * 16) * 128 + sx0);                     \
      b[n1_][1] = *(const short8*)(smem + 65536 + (BUF) * 32768 + (H) * 16384 +        \
                                   (brow + n1_ * 16) * 128 + sx1);                     \
    }                                                                                  \
  } while (0)

#define MM(HA, HB)                                                                     \
  do {                                                                                 \
    __builtin_amdgcn_s_setprio(1);                                                     \
    _Pragma("unroll") for (int m4_ = 0; m4_ < 4; ++m4_)                                \
      _Pragma("unroll") for (int n1_ = 0; n1_ < 2; ++n1_) {                            \
        acc[(HA) * 4 + m4_][(HB) * 2 + n1_] = __builtin_amdgcn_mfma_f32_16x16x32_bf16( \
            a[m4_][0], b[n1_][0], acc[(HA) * 4 + m4_][(HB) * 2 + n1_], 0, 0, 0);       \
        acc[(HA) * 4 + m4_][(HB) * 2 + n1_] = __builtin_amdgcn_mfma_f32_16x16x32_bf16( \
            a[m4_][1], b[n1_][1], acc[(HA) * 4 + m4_][(HB) * 2 + n1_], 0, 0, 0);       \
      }                                                                                \
    __builtin_amdgcn_s_setprio(0);                                                     \
  } while (0)

#define BARX   __builtin_amdgcn_s_barrier()
#define SB0    __builtin_amdgcn_sched_barrier(0)
#define WAITK  do { asm volatile("s_waitcnt lgkmcnt(0)" ::: "memory"); SB0; } while (0)
#define VMC4   asm volatile("s_waitcnt vmcnt(4)" ::: "memory")
#define VMC0   asm volatile("s_waitcnt vmcnt(0)" ::: "memory")

  // -------- prologue: tile0 all 4 halves + tile1.{Ah0, Bh1} --------
  STG_A(0, 0, 0); STG_A(0, 1, 0);
  STG_B(0, 0, 0); STG_B(0, 1, 0);
  STG_A(1, 0, 1);
  STG_B(1, 1, 1);
  VMC4;          // tile0 resident (tile1 halves = newest 4 loads outstanding)
  BARX;

#pragma unroll
  for (int i = 0; i < 4; ++i) {
    const int tO  = 2 * i + 1;
    const int tE2 = 2 * i + 2, tO2 = 2 * i + 3;
    const bool last = (i == 3);
    // P1
    LDA(0, 0); LDB(0, 0);
    STG_A(1, 1, tO);
    BARX; WAITK; MM(0, 0); SB0; BARX;
    // P2
    LDB(0, 1);
    STG_B(1, 0, tO);
    BARX; WAITK; MM(0, 1); SB0; BARX;
    // P3
    LDA(0, 1);
    if (!last) STG_A(0, 0, tE2);
    BARX; WAITK; MM(1, 1); SB0; BARX;
    // P4
    LDB(0, 0);
    if (!last) { STG_B(0, 1, tE2); VMC4; } else { VMC0; }
    BARX; WAITK; MM(1, 0); SB0; BARX;
    // P5
    LDA(1, 0); LDB(1, 0);
    if (!last) STG_A(0, 1, tE2);
    BARX; WAITK; MM(0, 0); SB0; BARX;
    // P6
    LDB(1, 1);
    if (!last) STG_B(0, 0, tE2);
    BARX; WAITK; MM(0, 1); SB0; BARX;
    // P7
    LDA(1, 1);
    if (!last) STG_A(1, 0, tO2);
    BARX; WAITK; MM(1, 1); SB0; BARX;
    // P8
    LDB(1, 0);
    if (!last) { STG_B(1, 1, tO2); VMC4; }
    BARX; WAITK; MM(1, 0); SB0; BARX;
  }

  // -------- epilogue: per-row min over each 128-col block + pair mask ------
  // All DMA drained (last stages waited by final-iter P4 vmcnt(0)); all LDS
  // reads complete (lgkmcnt(0) before each MFMA cluster) -> overlay smem.
  float    (*rmh)[2][4] = (float    (*)[2][4])(smem);          // [256][blk][wn]
  unsigned (*msk)[2][2] = (unsigned (*)[2][2])(smem + 8192);   // [256][blk][word]
  ((unsigned*)(smem + 8192))[tid]       = 0u;
  ((unsigned*)(smem + 8192))[tid + 512] = 0u;

#pragma unroll
  for (int m = 0; m < 8; ++m) {
    const int r = (m >> 2) * 128 + wm * 64 + (m & 3) * 16 + quad * 4;
#pragma unroll
    for (int reg = 0; reg < 4; ++reg) {
#pragma unroll
      for (int blk = 0; blk < 2; ++blk) {
        float v = fminf(acc[m][blk * 2 + 0][reg], acc[m][blk * 2 + 1][reg]);
#pragma unroll
        for (int s = 1; s < 16; s <<= 1) v = fminf(v, __shfl_xor(v, s, 64));
        if (c16 == 0) rmh[r + reg][blk][wn] = v;
      }
    }
  }
  __syncthreads();

#pragma unroll
  for (int m = 0; m < 8; ++m) {
    const int r = (m >> 2) * 128 + wm * 64 + (m & 3) * 16 + quad * 4;
#pragma unroll
    for (int reg = 0; reg < 4; ++reg) {
#pragma unroll
      for (int blk = 0; blk < 2; ++blk) {
        float thr = fminf(fminf(rmh[r + reg][blk][0], rmh[r + reg][blk][1]),
                          fminf(rmh[r + reg][blk][2], rmh[r + reg][blk][3])) + MARGIN;
#pragma unroll
        for (int n1 = 0; n1 < 2; ++n1) {
          if (acc[m][blk * 2 + n1][reg] <= thr) {
            int pb = wn * 16 + n1 * 8 + (c16 >> 1);   // pair 0..63 in block
            atomicOr(&msk[r + reg][blk][pb >> 5], 1u << (pb & 31));
          }
        }
      }
    }
  }
  __syncthreads();

  {
    const int r = tid >> 1, blk = tid & 1;
    float bm = fminf(fminf(rmh[r][blk][0], rmh[r][blk][1]),
                     fminf(rmh[r][blk][2], rmh[r][blk][3]));
    size_t o = (size_t)(row0 + r) * 64 + (size_t)blockIdx.y * 2 + blk;
    BM[o]         = bm;
    Msk[o * 2 + 0] = msk[r][blk][0];
    Msk[o * 2 + 1] = msk[r][blk][1];
  }
}

// ---------------- candidate expansion + exact fp32 recheck ----------------
__global__ __launch_bounds__(256) void vq_select(const float* __restrict__ X,
                                                 const float* __restrict__ CB,
                                                 const float* __restrict__ xsq,
                                                 const float* __restrict__ BM,
                                                 const unsigned int* __restrict__ Msk,
                                                 int* __restrict__ idx_i,
                                                 float* __restrict__ idx_f) {
  __shared__ unsigned short cand[4][128];
  __shared__ int cnt[4];
  const int lane = threadIdx.x & 63;
  const int w    = threadIdx.x >> 6;
  const int row  = blockIdx.x * 4 + w;

  if (lane == 0) cnt[w] = 0;
  __syncthreads();

  const size_t bo = (size_t)row * 64 + lane;
  float bmv = BM[bo];
  float g = bmv;
#pragma unroll
  for (int m = 1; m < 64; m <<= 1) g = fminf(g, __shfl_xor(g, m, 64));
  if (bmv <= g + MARGIN) {
    unsigned m0 = Msk[bo * 2 + 0], m1 = Msk[bo * 2 + 1];
    while (m0) {
      int p = __ffs(m0) - 1; m0 &= m0 - 1;
      int base = lane * 128 + p * 2;
      int o = atomicAdd(&cnt[w], 2);
      if (o + 1 < 128) { cand[w][o] = (unsigned short)base; cand[w][o + 1] = (unsigned short)(base + 1); }
    }
    while (m1) {
      int p = __ffs(m1) - 1; m1 &= m1 - 1;
      int base = lane * 128 + 64 + p * 2;
      int o = atomicAdd(&cnt[w], 2);
      if (o + 1 < 128) { cand[w][o] = (unsigned short)base; cand[w][o + 1] = (unsigned short)(base + 1); }
    }
  }
  __syncthreads();

  int n = cnt[w]; n = n > 128 ? 128 : n;
  float bd = __builtin_inff();
  int   bi = 0x7fffffff;
  const float4* xr = (const float4*)(X + (size_t)row * DDIM);
  const float   xs = xsq[row];
  for (int c = lane; c < n; c += 64) {
    int code = cand[w][c];
    const float4* cr = (const float4*)(CB + (size_t)code * DDIM);
    float acc = 0.f;   // EXACT chain: k ascending, single fp32 fma accumulator
#pragma unroll 4
    for (int k = 0; k < 128; ++k) {
      float4 xv = xr[k], cv = cr[k];
      acc = fmaf(xv.x, cv.x, acc);
      acc = fmaf(xv.y, cv.y, acc);
      acc = fmaf(xv.z, cv.z, acc);
      acc = fmaf(xv.w, cv.w, acc);
    }
    float d = fmaf(2.f, acc, xs);
    if (d < bd || (d == bd && code < bi)) { bd = d; bi = code; }
  }
#pragma unroll
  for (int m = 1; m < 64; m <<= 1) {
    float od = __shfl_xor(bd, m, 64);
    int   oi = __shfl_xor(bi, m, 64);
    if (od < bd || (od == bd && oi < bi)) { bd = od; bi = oi; }
  }
  if (lane == 0) { idx_i[row] = bi; idx_f[row] = (float)bi; }
}

// ---------------- gather codebook rows into both outputs ----------------
__global__ __launch_bounds__(256) void vq_gather(const float* __restrict__ CB,
                                                 const int* __restrict__ idx_i,
                                                 float* __restrict__ out_codes,
                                                 float* __restrict__ out_zqx) {
  const int t = threadIdx.x;
  const int r = blockIdx.x * 2 + (t >> 7);
  const int q = t & 127;
  const int k = idx_i[r];
  float4 v = *(const float4*)(CB + (size_t)k * DDIM + q * 4);
  *(float4*)(out_codes + (size_t)r * DDIM + q * 4) = v;
  *(float4*)(out_zqx   + (size_t)r * DDIM + q * 4) = v;
}

// ---------------- fallback: round-2 fp32 fused GEMM+argmin (known-good) ----
constexpr int FMT = 64, FNT = 128, FDC = 32;
constexpr int FAS = FMT + 2, FBS = FNT + 2;
__global__ __launch_bounds__(256, 2) void vq_argmin_fb(const float* __restrict__ X,
                                                       const float* __restrict__ CB,
                                                       const float* __restrict__ xsq,
                                                       int* __restrict__ idx_i,
                                                       float* __restrict__ idx_f) {
  __shared__ float As[FDC][FAS];
  __shared__ float Bs[FDC][FBS];
  const int tid = threadIdx.x;
  const int tx = tid & 15, ty = tid >> 4;
  const int row_base = blockIdx.x * FMT;
  float xs[4];
#pragma unroll
  for (int i = 0; i < 4; ++i) xs[i] = xsq[row_base + ty * 4 + i];
  float bestv[4]; int besti[4];
#pragma unroll
  for (int i = 0; i < 4; ++i) { bestv[i] = __builtin_inff(); besti[i] = 0; }
  for (int c0 = 0; c0 < KC; c0 += FNT) {
    float acc[4][8];
#pragma unroll
    for (int i = 0; i < 4; ++i)
#pragma unroll
      for (int j = 0; j < 8; ++j) acc[i][j] = 0.f;
    for (int d0 = 0; d0 < DDIM; d0 += FDC) {
      __syncthreads();
#pragma unroll
      for (int s = 0; s < 2; ++s) {
        int f = tid + 256 * s; int r = f >> 3, q = f & 7;
        float4 v = *(const float4*)(X + (size_t)(row_base + r) * DDIM + d0 + q * 4);
        As[q * 4 + 0][r] = v.x; As[q * 4 + 1][r] = v.y;
        As[q * 4 + 2][r] = v.z; As[q * 4 + 3][r] = v.w;
      }
#pragma unroll
      for (int s = 0; s < 4; ++s) {
        int f = tid + 256 * s; int r = f >> 3, q = f & 7;
        float4 v = *(const float4*)(CB + (size_t)(c0 + r) * DDIM + d0 + q * 4);
        Bs[q * 4 + 0][r] = v.x; Bs[q * 4 + 1][r] = v.y;
        Bs[q * 4 + 2][r] = v.z; Bs[q * 4 + 3][r] = v.w;
      }
      __syncthreads();
#pragma unroll
      for (int kk = 0; kk < FDC; ++kk) {
        float a[4], b[8];
        *(float2*)&a[0] = *(const float2*)&As[kk][ty * 4 + 0];
        *(float2*)&a[2] = *(const float2*)&As[kk][ty * 4 + 2];
        *(float2*)&b[0] = *(const float2*)&Bs[kk][tx * 4 + 0];
        *(float2*)&b[2] = *(const float2*)&Bs[kk][tx * 4 + 2];
        *(float2*)&b[4] = *(const float2*)&Bs[kk][64 + tx * 4 + 0];
        *(float2*)&b[6] = *(const float2*)&Bs[kk][64 + tx * 4 + 2];
#pragma unroll
        for (int i = 0; i < 4; ++i)
#pragma unroll
          for (int j = 0; j < 8; ++j) acc[i][j] = fmaf(a[i], b[j], acc[i][j]);
      }
    }
#pragma unroll
    for (int j = 0; j < 8; ++j) {
      int c = c0 + ((j < 4) ? (tx * 4 + j) : (64 + tx * 4 + (j - 4)));
#pragma unroll
      for (int i = 0; i < 4; ++i) {
        float d = fmaf(2.f, acc[i][j], xs[i]);
        if (d < bestv[i] || (d == bestv[i] && c < besti[i])) { bestv[i] = d; besti[i] = c; }
      }
    }
  }
#pragma unroll
  for (int m = 1; m < 16; m <<= 1) {
#pragma unroll
    for (int i = 0; i < 4; ++i) {
      float ov = __shfl_xor(bestv[i], m, 64);
      int   oi = __shfl_xor(besti[i], m, 64);
      if (ov < bestv[i] || (ov == bestv[i] && oi < besti[i])) { bestv[i] = ov; besti[i] = oi; }
    }
  }
  if (tx == 0) {
#pragma unroll
    for (int i = 0; i < 4; ++i) {
      int r = row_base + ty * 4 + i;
      idx_i[r] = besti[i];
      idx_f[r] = (float)besti[i];
    }
  }
}

extern "C" void kernel_launch(void* const* d_in, const int* in_sizes, int n_in,
                              void* d_out, int out_size, void* d_ws, size_t ws_size,
                              hipStream_t stream) {
  const float* X  = (const float*)d_in[0];
  const float* CB = (const float*)d_in[1];

  float* out       = (float*)d_out;
  float* out_codes = out;
  float* out_zqx   = out + (size_t)BN * DDIM;
  float* out_idxf  = out + 2 * (size_t)BN * DDIM;

  unsigned char* w0 = (unsigned char*)d_ws;
  const size_t NEED = (64ull << 20) + 2 * (size_t)BN * 4;

  if (ws_size >= NEED) {
    unsigned short* Xb  = (unsigned short*)w0;                    // 32 MB
    unsigned short* CBb = (unsigned short*)(w0 + (32ull << 20));  //  8 MB
    float*        BM    = (float*)(w0 + (40ull << 20));           //  8 MB
    unsigned int* Msk   = (unsigned int*)(w0 + (48ull << 20));    // 16 MB
    float*        xsq   = (float*)(w0 + (64ull << 20));
    int*          idx_i = (int*)(w0 + (64ull << 20) + (size_t)BN * 4);

    vq_xsq   <<<BN / 4, 256, 0, stream>>>(X, xsq);
    vq_cvt   <<<512, 256, 0, stream>>>(X,  Xb,  BN * (DDIM / 4));
    vq_cvt   <<<128, 256, 0, stream>>>(CB, CBb, KC * (DDIM / 4));
    vq_gemm8 <<<dim3(BN / 256, KC / 256), 512, 0, stream>>>(Xb, CBb, BM, Msk);
    vq_select<<<BN / 4, 256, 0, stream>>>(X, CB, xsq, BM, Msk, idx_i, out_idxf);
    vq_gather<<<BN / 2, 256, 0, stream>>>(CB, idx_i, out_codes, out_zqx);
  } else {
    float* xsq   = (float*)w0;
    int*   idx_i = (int*)(w0 + (size_t)BN * 4);
    vq_xsq      <<<BN / 4, 256, 0, stream>>>(X, xsq);
    vq_argmin_fb<<<BN / FMT, 256, 0, stream>>>(X, CB, xsq, idx_i, out_idxf);
    vq_gather   <<<BN / 2, 256, 0, stream>>>(CB, idx_i, out_codes, out_zqx);
  }
}